// Round 5
// baseline (131.390 us; speedup 1.0000x reference)
//
#include <hip/hip_runtime.h>
#include <cstdint>
#include <cstddef>

typedef __attribute__((ext_vector_type(8))) short bf16x8;
typedef __attribute__((ext_vector_type(4))) float f32x4;

#define POOLK 12544   // K order: ij*256 + c

// T (channel-last bf16 feats) level offsets in shorts
#define TOFF2 0
#define TOFF3 16777216
#define TOFF4 20971520
#define TOFF5 22020096

__device__ __forceinline__ void gld16(const void* g, void* l) {
    __builtin_amdgcn_global_load_lds(
        (const __attribute__((address_space(1))) void*)g,
        (__attribute__((address_space(3))) void*)l, 16, 0, 0);
}
__device__ __forceinline__ unsigned short f32_to_bf16(float f) {
    union { float f; unsigned u; } x; x.f = f;
    return (unsigned short)((x.u + 0x7FFFu + ((x.u >> 16) & 1u)) >> 16);
}
__device__ __forceinline__ float bf16_to_f32(unsigned short s) {
    return __uint_as_float(((unsigned)s) << 16);
}

// ---------- feature transpose, 128-pos tiles: [256][HW] f32 -> [HW][256] bf16 ----------
// 512 B contiguous read per channel (32 lanes x float4); LDS [128][256] bf16 with
// XOR swizzle c ^= ((p>>2)&7)<<3 (writes 4-way, reads conflict-free); 4 KB output runs.
__global__ __launch_bounds__(256) void feat_tr_kernel(
    const float* __restrict__ f2, const float* __restrict__ f3,
    const float* __restrict__ f4, const float* __restrict__ f5,
    unsigned short* __restrict__ T)
{
    __shared__ __align__(16) unsigned short sh[128 * 256];   // 64 KB
    int b = blockIdx.x;
    const float* src; unsigned short* dst; int P;
    if (b < 512)      { src = f2; dst = T + TOFF2; P = 65536; }
    else if (b < 640) { src = f3; dst = T + TOFF3; P = 16384; b -= 512; }
    else if (b < 672) { src = f4; dst = T + TOFF4; P = 4096;  b -= 640; }
    else              { src = f5; dst = T + TOFF5; P = 1024;  b -= 672; }
    const int p0 = b * 128;
    const int t = threadIdx.x;
    const int lane5 = t & 31;
    const int x4 = lane5 * 4;                 // position base within tile
    const int fx = (lane5 & 7) << 3;          // write-side XOR (p>>2 == lane5)

#pragma unroll
    for (int it = 0; it < 8; ++it) {
        float4 v[4];
        int cs[4];
#pragma unroll
        for (int u = 0; u < 4; ++u) {
            cs[u] = it * 32 + u * 8 + (t >> 5);
            v[u] = *(const float4*)(src + (size_t)cs[u] * P + p0 + x4);
        }
#pragma unroll
        for (int u = 0; u < 4; ++u) {
            const int cp = cs[u] ^ fx;
            float vv[4] = {v[u].x, v[u].y, v[u].z, v[u].w};
#pragma unroll
            for (int i = 0; i < 4; ++i)
                sh[(x4 + i) * 256 + cp] = f32_to_bf16(vv[i]);
        }
    }
    __syncthreads();

    const int c0 = lane5 * 8;
#pragma unroll
    for (int oz = 0; oz < 16; ++oz) {
        const int pp = oz * 8 + (t >> 5);
        const int cr = c0 ^ (((pp >> 2) & 7) << 3);
        const bf16x8 vv = *(const bf16x8*)&sh[pp * 256 + cr];
        *(bf16x8*)(dst + (size_t)(p0 + pp) * 256 + c0) = vv;
    }
}

// ---------- merged: ROI gather (blocks 0-1023) + convw transpose + fc cvts ----------
__global__ __launch_bounds__(256) void gather_prep_kernel(
    const unsigned short* __restrict__ T, const float* __restrict__ rois,
    unsigned short* __restrict__ pooled, int nroi,
    const float* __restrict__ conv_w, unsigned short* __restrict__ convw_bf,
    const float* __restrict__ fc1_w, unsigned short* __restrict__ fc1w_bf,
    const float* __restrict__ fc2_w, unsigned short* __restrict__ fc2w_bf)
{
    const int t = threadIdx.x;
    int b = blockIdx.x;

    if (b >= 1024) {
        b -= 1024;
        if (b < 2048) {          // ---- conv_w [o][c][ij] -> [o][ij*256+c], half per block
            __shared__ unsigned short sh[6272];
            const int o = b >> 1, half = b & 1;
            const float* srow = conv_w + (size_t)o * POOLK + half * 6272;
            for (int k = t; k < 6272; k += 256) sh[k] = f32_to_bf16(srow[k]);
            __syncthreads();
            unsigned short* drow = convw_bf + (size_t)o * POOLK + half * 128;
            for (int k = t; k < 6272; k += 256) {
                const int ij = k >> 7, cl = k & 127;
                drow[ij * 256 + cl] = sh[cl * 49 + ij];
            }
        } else {                 // ---- fc weight conversions (512 blocks x 4096 elems)
            b -= 2048;
            const float* src = (b < 256) ? fc1_w : fc2_w;
            unsigned short* dst = (b < 256) ? fc1w_bf : fc2w_bf;
            const int base = (b & 255) * 4096 + t * 16;
#pragma unroll
            for (int u = 0; u < 4; ++u) {
                const float4 v = *(const float4*)(src + base + u * 4);
                ushort4 o4;
                o4.x = f32_to_bf16(v.x); o4.y = f32_to_bf16(v.y);
                o4.z = f32_to_bf16(v.z); o4.w = f32_to_bf16(v.w);
                *(ushort4*)(dst + base + u * 4) = o4;
            }
        }
        return;
    }

    // ---- ROI gather from channel-last T; pooled[n][ij*256+c]; zero pad rows
    const int n = b;
    unsigned short* orow = pooled + (size_t)n * POOLK;
    if (n >= nroi) {
        const bf16x8 z = {};
        for (int k = t * 8; k < POOLK; k += 2048) *(bf16x8*)(orow + k) = z;
        return;
    }
    __shared__ int sy0[7], sy1[7], sx0[7], sx1[7];
    __shared__ float swy[7], swx[7], svy[7], svx[7];

    const float rx1 = rois[n*4+0], ry1 = rois[n*4+1];
    const float rx2 = rois[n*4+2], ry2 = rois[n*4+3];
    int lvl = (int)rintf(log2f(sqrtf((ry2-ry1)*(rx2-rx1)) * (1.0f/224.0f))) + 4;
    lvl = lvl < 2 ? 2 : (lvl > 5 ? 5 : lvl);
    const int W = 256 >> (lvl - 2);
    const float Hm1 = (float)(W - 1);
    const unsigned short* Tl = T + (lvl == 2 ? TOFF2 : (lvl == 3 ? TOFF3 : (lvl == 4 ? TOFF4 : TOFF5)));

    if (t < 7) {
        const float tt = (float)t / 6.0f;
        const float by1 = ry1*(1.0f/1024.0f), by2 = ry2*(1.0f/1024.0f);
        const float bx1 = rx1*(1.0f/1024.0f), bx2 = rx2*(1.0f/1024.0f);
        const float ys = (by1 + (by2 - by1) * tt) * Hm1;
        const float xs = (bx1 + (bx2 - bx1) * tt) * Hm1;
        const float yf = floorf(ys), xf = floorf(xs);
        swy[t] = ys - yf;  swx[t] = xs - xf;
        sy0[t] = (int)fminf(fmaxf(yf,        0.0f), Hm1);
        sy1[t] = (int)fminf(fmaxf(yf + 1.0f, 0.0f), Hm1);
        sx0[t] = (int)fminf(fmaxf(xf,        0.0f), Hm1);
        sx1[t] = (int)fminf(fmaxf(xf + 1.0f, 0.0f), Hm1);
        svy[t] = (ys >= 0.0f && ys <= Hm1) ? 1.0f : 0.0f;
        svx[t] = (xs >= 0.0f && xs <= Hm1) ? 1.0f : 0.0f;
    }
    __syncthreads();

    const int g  = t >> 5;
    const int c0 = (t & 31) * 8;
#pragma unroll
    for (int it = 0; it < 7; ++it) {
        const int pos = it * 8 + g;
        if (pos >= 49) break;
        const int i = pos / 7, j = pos % 7;
        const int y0 = sy0[i], y1 = sy1[i], x0 = sx0[j], x1 = sx1[j];
        const float wy = swy[i], wx = swx[j];
        const float scale = svy[i] * svx[j];
        const bf16x8 v00 = *(const bf16x8*)(Tl + ((size_t)(y0*W + x0))*256 + c0);
        const bf16x8 v01 = *(const bf16x8*)(Tl + ((size_t)(y0*W + x1))*256 + c0);
        const bf16x8 v10 = *(const bf16x8*)(Tl + ((size_t)(y1*W + x0))*256 + c0);
        const bf16x8 v11 = *(const bf16x8*)(Tl + ((size_t)(y1*W + x1))*256 + c0);
        bf16x8 o;
#pragma unroll
        for (int jj = 0; jj < 8; ++jj) {
            const float f00 = bf16_to_f32((unsigned short)v00[jj]);
            const float f01 = bf16_to_f32((unsigned short)v01[jj]);
            const float f10 = bf16_to_f32((unsigned short)v10[jj]);
            const float f11 = bf16_to_f32((unsigned short)v11[jj]);
            const float top = f00 + (f01 - f00) * wx;
            const float bot = f10 + (f11 - f10) * wx;
            o[jj] = (short)f32_to_bf16((top + (bot - top) * wy) * scale);
        }
        *(bf16x8*)(orow + pos * 256 + c0) = o;
    }
}

// ---------- fallback ROI (direct f32 gather), also zeroes pad rows ----------
__global__ __launch_bounds__(256) void roi_direct_kernel(
    const float* __restrict__ feat2, const float* __restrict__ feat3,
    const float* __restrict__ feat4, const float* __restrict__ feat5,
    const float* __restrict__ rois, unsigned short* __restrict__ pooled, int nroi)
{
    const int n = blockIdx.x;
    const int tid = threadIdx.x;
    unsigned short* orow = pooled + (size_t)n * POOLK;
    if (n >= nroi) {
        const bf16x8 z = {};
        for (int k = tid * 8; k < POOLK; k += 2048) *(bf16x8*)(orow + k) = z;
        return;
    }
    __shared__ int sy0[7], sy1[7], sx0[7], sx1[7];
    __shared__ float swy[7], swx[7], svy[7], svx[7];
    const float rx1 = rois[n*4+0], ry1 = rois[n*4+1];
    const float rx2 = rois[n*4+2], ry2 = rois[n*4+3];
    int lvl = (int)rintf(log2f(sqrtf((ry2-ry1)*(rx2-rx1)) * (1.0f/224.0f))) + 4;
    lvl = lvl < 2 ? 2 : (lvl > 5 ? 5 : lvl);
    const int H = 256 >> (lvl - 2);
    const float Hm1 = (float)(H - 1);
    const float* feat = lvl==2 ? feat2 : (lvl==3 ? feat3 : (lvl==4 ? feat4 : feat5));
    if (tid < 7) {
        const float t = (float)tid / 6.0f;
        const float by1 = ry1*(1.0f/1024.0f), by2 = ry2*(1.0f/1024.0f);
        const float bx1 = rx1*(1.0f/1024.0f), bx2 = rx2*(1.0f/1024.0f);
        const float ys = (by1 + (by2-by1)*t) * Hm1;
        const float xs = (bx1 + (bx2-bx1)*t) * Hm1;
        const float yf = floorf(ys), xf = floorf(xs);
        swy[tid] = ys - yf;  swx[tid] = xs - xf;
        sy0[tid] = (int)fminf(fmaxf(yf,      0.0f), Hm1);
        sy1[tid] = (int)fminf(fmaxf(yf+1.0f, 0.0f), Hm1);
        sx0[tid] = (int)fminf(fmaxf(xf,      0.0f), Hm1);
        sx1[tid] = (int)fminf(fmaxf(xf+1.0f, 0.0f), Hm1);
        svy[tid] = (ys >= 0.0f && ys <= Hm1) ? 1.0f : 0.0f;
        svx[tid] = (xs >= 0.0f && xs <= Hm1) ? 1.0f : 0.0f;
    }
    __syncthreads();
    const int HW = H * H;
    for (int e = tid; e < POOLK; e += 256) {
        const int c = e / 49, ij = e % 49, i = ij / 7, j = ij % 7;
        const float* p = feat + c * HW;
        const int y0 = sy0[i], y1 = sy1[i], x0 = sx0[j], x1 = sx1[j];
        const float wy = swy[i], wx = swx[j];
        const float v00 = p[y0*H + x0], v01 = p[y0*H + x1];
        const float v10 = p[y1*H + x0], v11 = p[y1*H + x1];
        float v = v00*(1.0f-wy)*(1.0f-wx) + v01*(1.0f-wy)*wx
                + v10*wy*(1.0f-wx)        + v11*wy*wx;
        v *= svy[i] * svx[j];
        orow[ij*256 + c] = f32_to_bf16(v);
    }
}

// ---------- direct-path weight prep (tier 2 only) ----------
__global__ __launch_bounds__(256) void wprep_kernel(
    const float* __restrict__ conv_w, unsigned short* __restrict__ convw_bf,
    const float* __restrict__ fc1_w, unsigned short* __restrict__ fc1w_bf,
    const float* __restrict__ fc2_w, unsigned short* __restrict__ fc2w_bf)
{
    const int t = threadIdx.x;
    int b = blockIdx.x;
    if (b < 2048) {
        __shared__ unsigned short sh[6272];
        const int o = b >> 1, half = b & 1;
        const float* srow = conv_w + (size_t)o * POOLK + half * 6272;
        for (int k = t; k < 6272; k += 256) sh[k] = f32_to_bf16(srow[k]);
        __syncthreads();
        unsigned short* drow = convw_bf + (size_t)o * POOLK + half * 128;
        for (int k = t; k < 6272; k += 256) {
            const int ij = k >> 7, cl = k & 127;
            drow[ij * 256 + cl] = sh[cl * 49 + ij];
        }
        return;
    }
    b -= 2048;
    const float* src = (b < 256) ? fc1_w : fc2_w;
    unsigned short* dst = (b < 256) ? fc1w_bf : fc2w_bf;
    const int base = (b & 255) * 4096 + t * 16;
#pragma unroll
    for (int u = 0; u < 4; ++u) {
        const float4 v = *(const float4*)(src + base + u * 4);
        ushort4 o4;
        o4.x = f32_to_bf16(v.x); o4.y = f32_to_bf16(v.y);
        o4.z = f32_to_bf16(v.z); o4.w = f32_to_bf16(v.w);
        *(ushort4*)(dst + base + u * 4) = o4;
    }
}

// ---------- bf16 BT-GEMM, 128x128 tile, BK=32, double-buffered, split-K ----------
__global__ __launch_bounds__(256, 2) void gemm_bt(
    const unsigned short* __restrict__ A, const unsigned short* __restrict__ B,
    float* __restrict__ Cpart, int K, int Kper, int nz)
{
    __shared__ __align__(16) unsigned short At[2][128*32];
    __shared__ __align__(16) unsigned short Bt[2][128*32];
    const int tid  = threadIdx.x;
    const int lane = tid & 63;
    const int bid  = blockIdx.x;
    const int z  = bid % nz;
    const int iq = bid / nz;
    const int bx = iq & 7, by = iq >> 3;
    const int wm = (tid >> 6) >> 1, wn = (tid >> 6) & 1;
    const size_t k0 = (size_t)z * Kper;

    const int r1 = tid >> 2;
    const int q  = tid & 3;
    const int csw = (q ^ (r1 & 3)) * 8;
    const unsigned short* Ag = A + ((size_t)(by * 128 + r1)) * K + k0 + csw;
    const unsigned short* Bg = B + ((size_t)(bx * 128 + r1)) * K + k0 + csw;
    const int nit = Kper >> 5;

    gld16(Ag,                  &At[0][tid * 8]);
    gld16(Ag + (size_t)64 * K, &At[0][(tid + 256) * 8]);
    gld16(Bg,                  &Bt[0][tid * 8]);
    gld16(Bg + (size_t)64 * K, &Bt[0][(tid + 256) * 8]);

    f32x4 acc[4][4] = {};
    const int fr = lane & 15;
    const int fq = lane >> 4;
    const int rslot = (fq ^ (fr & 3)) * 8;

    int buf = 0;
    for (int it = 0; it < nit; ++it) {
        if (it + 1 < nit) {
            const size_t ko = (size_t)(it + 1) * 32;
            gld16(Ag + ko,                  &At[buf ^ 1][tid * 8]);
            gld16(Ag + (size_t)64 * K + ko, &At[buf ^ 1][(tid + 256) * 8]);
            gld16(Bg + ko,                  &Bt[buf ^ 1][tid * 8]);
            gld16(Bg + (size_t)64 * K + ko, &Bt[buf ^ 1][(tid + 256) * 8]);
            asm volatile("s_waitcnt vmcnt(4)" ::: "memory");
        } else {
            asm volatile("s_waitcnt vmcnt(0)" ::: "memory");
        }
        __syncthreads();

        bf16x8 a[4], b[4];
#pragma unroll
        for (int mi = 0; mi < 4; ++mi)
            a[mi] = *(const bf16x8*)&At[buf][(wm*64 + mi*16 + fr) * 32 + rslot];
#pragma unroll
        for (int ni = 0; ni < 4; ++ni)
            b[ni] = *(const bf16x8*)&Bt[buf][(wn*64 + ni*16 + fr) * 32 + rslot];
        __builtin_amdgcn_s_setprio(1);
#pragma unroll
        for (int mi = 0; mi < 4; ++mi)
#pragma unroll
            for (int ni = 0; ni < 4; ++ni)
                acc[mi][ni] = __builtin_amdgcn_mfma_f32_16x16x32_bf16(
                    a[mi], b[ni], acc[mi][ni], 0, 0, 0);
        __builtin_amdgcn_s_setprio(0);
        __syncthreads();
        buf ^= 1;
    }

    float* Cp = Cpart + (size_t)z * (1024 * 1024);
    const int row0 = by * 128 + wm * 64;
    const int col0 = bx * 128 + wn * 64;
#pragma unroll
    for (int mi = 0; mi < 4; ++mi)
#pragma unroll
        for (int ni = 0; ni < 4; ++ni)
#pragma unroll
            for (int r = 0; r < 4; ++r)
                Cp[(size_t)(row0 + mi*16 + fq*4 + r) * 1024 + col0 + ni*16 + fr]
                    = acc[mi][ni][r];
}

// ---------- reduce split-K partials + BN -> bf16 ----------
__global__ void reduce_bn_kernel(const float* __restrict__ part,
    const float* __restrict__ bias, const float* __restrict__ gamma,
    const float* __restrict__ beta, const float* __restrict__ mean,
    const float* __restrict__ var, unsigned short* __restrict__ out, int nz)
{
    const int i4 = (blockIdx.x * 256 + threadIdx.x) * 4;
    const int n = i4 & 1023;
    float4 v = make_float4(0.f, 0.f, 0.f, 0.f);
    for (int zz = 0; zz < nz; ++zz) {
        const float4 p = *(const float4*)(part + (size_t)zz * 1048576 + i4);
        v.x += p.x; v.y += p.y; v.z += p.z; v.w += p.w;
    }
    const float4 bi = *(const float4*)(bias + n);
    const float4 ga = *(const float4*)(gamma + n);
    const float4 be = *(const float4*)(beta + n);
    const float4 me = *(const float4*)(mean + n);
    const float4 va = *(const float4*)(var + n);
    ushort4 o;
    o.x = f32_to_bf16((v.x + bi.x - me.x) * __frsqrt_rn(va.x + 0.001f) * ga.x + be.x);
    o.y = f32_to_bf16((v.y + bi.y - me.y) * __frsqrt_rn(va.y + 0.001f) * ga.y + be.y);
    o.z = f32_to_bf16((v.z + bi.z - me.z) * __frsqrt_rn(va.z + 0.001f) * ga.z + be.z);
    o.w = f32_to_bf16((v.w + bi.w - me.w) * __frsqrt_rn(va.w + 0.001f) * ga.w + be.w);
    *(ushort4*)(out + i4) = o;
}

// ---------- fused 64x64 FC GEMM (K=1024, BK=32, double-buffered) ----------
__global__ __launch_bounds__(256) void gemm64_fused(
    const unsigned short* __restrict__ A, const unsigned short* __restrict__ B,
    const float* __restrict__ bias, unsigned short* __restrict__ out, int relu)
{
    __shared__ __align__(16) unsigned short At[2][64*32];
    __shared__ __align__(16) unsigned short Bt[2][64*32];
    const int tid = threadIdx.x, lane = tid & 63;
    const int w = tid >> 6, wm = w >> 1, wn = w & 1;
    const int r1 = tid >> 2;
    const int q  = tid & 3;
    const int csw = (q ^ (r1 & 3)) * 8;
    const unsigned short* Ag = A + (size_t)(blockIdx.y*64 + r1) * 1024 + csw;
    const unsigned short* Bg = B + (size_t)(blockIdx.x*64 + r1) * 1024 + csw;
    const int fr = lane & 15, fq = lane >> 4;
    const int rslot = (fq ^ (fr & 3)) * 8;

    gld16(Ag, &At[0][tid * 8]);
    gld16(Bg, &Bt[0][tid * 8]);

    f32x4 acc[2][2] = {};
    int buf = 0;
    for (int it = 0; it < 32; ++it) {
        if (it + 1 < 32) {
            const int ko = (it + 1) * 32;
            gld16(Ag + ko, &At[buf ^ 1][tid * 8]);
            gld16(Bg + ko, &Bt[buf ^ 1][tid * 8]);
            asm volatile("s_waitcnt vmcnt(2)" ::: "memory");
        } else {
            asm volatile("s_waitcnt vmcnt(0)" ::: "memory");
        }
        __syncthreads();
        bf16x8 a[2], b[2];
#pragma unroll
        for (int mi = 0; mi < 2; ++mi)
            a[mi] = *(const bf16x8*)&At[buf][(wm*32 + mi*16 + fr) * 32 + rslot];
#pragma unroll
        for (int ni = 0; ni < 2; ++ni)
            b[ni] = *(const bf16x8*)&Bt[buf][(wn*32 + ni*16 + fr) * 32 + rslot];
        __builtin_amdgcn_s_setprio(1);
#pragma unroll
        for (int mi = 0; mi < 2; ++mi)
#pragma unroll
            for (int ni = 0; ni < 2; ++ni)
                acc[mi][ni] = __builtin_amdgcn_mfma_f32_16x16x32_bf16(
                    a[mi], b[ni], acc[mi][ni], 0, 0, 0);
        __builtin_amdgcn_s_setprio(0);
        __syncthreads();
        buf ^= 1;
    }
    const int row0 = blockIdx.y*64 + wm*32;
    const int col0 = blockIdx.x*64 + wn*32;
#pragma unroll
    for (int mi = 0; mi < 2; ++mi)
#pragma unroll
        for (int ni = 0; ni < 2; ++ni)
#pragma unroll
            for (int r = 0; r < 4; ++r) {
                const int row = row0 + mi*16 + fq*4 + r;
                const int col = col0 + ni*16 + fr;
                float v = acc[mi][ni][r] + bias[col];
                if (relu) v = fmaxf(v, 0.0f);
                out[(size_t)row * 1024 + col] = f32_to_bf16(v);
            }
}

// ---------- cls/bbox heads + softmax ----------
__global__ __launch_bounds__(256) void head_kernel(
    const unsigned short* __restrict__ h2,
    const float* __restrict__ cls_w, const float* __restrict__ cls_b,
    const float* __restrict__ bbox_w, const float* __restrict__ bbox_b,
    float* __restrict__ out)
{
    const int roi = blockIdx.x * 4 + (threadIdx.x >> 6);
    const int lane = threadIdx.x & 63;
    const unsigned short* hrow = h2 + (size_t)roi * 1024;
    float hv[16];
#pragma unroll
    for (int j = 0; j < 16; ++j)
        hv[j] = bf16_to_f32(hrow[lane*16 + j]);
    float r[10];
#pragma unroll
    for (int o = 0; o < 10; ++o) {
        const float* w = (o < 2) ? (cls_w + o*1024) : (bbox_w + (size_t)(o-2)*1024);
        float s = 0.f;
#pragma unroll
        for (int j = 0; j < 16; ++j) s += hv[j] * w[lane*16 + j];
#pragma unroll
        for (int off = 32; off > 0; off >>= 1) s += __shfl_xor(s, off);
        r[o] = s;
    }
    if (lane == 0) {
        const float l0 = r[0] + cls_b[0], l1 = r[1] + cls_b[1];
        out[roi*2+0] = l0; out[roi*2+1] = l1;
        const float m = fmaxf(l0, l1);
        const float e0 = expf(l0 - m), e1 = expf(l1 - m);
        const float inv = 1.0f / (e0 + e1);
        out[2000 + roi*2 + 0] = e0 * inv;
        out[2000 + roi*2 + 1] = e1 * inv;
#pragma unroll
        for (int qq = 0; qq < 8; ++qq) out[4000 + roi*8 + qq] = r[2+qq] + bbox_b[qq];
    }
}

// ---------- launcher ----------
extern "C" void kernel_launch(void* const* d_in, const int* in_sizes, int n_in,
                              void* d_out, int out_size, void* d_ws, size_t ws_size,
                              hipStream_t stream)
{
    const float* feat2   = (const float*)d_in[0];
    const float* feat3   = (const float*)d_in[1];
    const float* feat4   = (const float*)d_in[2];
    const float* feat5   = (const float*)d_in[3];
    const float* rois    = (const float*)d_in[4];
    const float* conv_w  = (const float*)d_in[5];
    const float* conv_b  = (const float*)d_in[6];
    const float* bn_gamma= (const float*)d_in[7];
    const float* bn_beta = (const float*)d_in[8];
    const float* bn_mean = (const float*)d_in[9];
    const float* bn_var  = (const float*)d_in[10];
    const float* fc1_w   = (const float*)d_in[11];
    const float* fc1_b   = (const float*)d_in[12];
    const float* fc2_w   = (const float*)d_in[13];
    const float* fc2_b   = (const float*)d_in[14];
    const float* cls_w   = (const float*)d_in[15];
    const float* cls_b   = (const float*)d_in[16];
    const float* bbox_w  = (const float*)d_in[17];
    const float* bbox_b  = (const float*)d_in[18];
    float* out = (float*)d_out;
    const int nroi = in_sizes[4] / 4;

    const size_t fixedBytes = (size_t)25690112 + 25690112 + 5 * (size_t)2097152;
    const size_t needA = fixedBytes + (size_t)44564480;   // ~106.5 MB
    const int tier = (ws_size >= needA) ? 1 : 2;
    const size_t regionA = tier == 1 ? (size_t)44564480 : (size_t)16777216;
    const int nzc  = tier == 1 ? 8 : 4;
    const int Kper = tier == 1 ? 1568 : 3136;

    char* ws = (char*)d_ws;
    size_t off = 0;
    auto alloc = [&](size_t bytes) {
        void* p = ws + off; off += (bytes + 255) & ~(size_t)255; return p;
    };
    char* rA = (char*)alloc(regionA);     // T feats (early) aliased by split-K partials (late)
    unsigned short* T    = (unsigned short*)rA;
    float*          part = (float*)rA;
    unsigned short* pooled   = (unsigned short*)alloc((size_t)1024 * POOLK * 2);
    unsigned short* convw_bf = (unsigned short*)alloc((size_t)1024 * POOLK * 2);
    unsigned short* fc1w_bf  = (unsigned short*)alloc((size_t)1048576 * 2);
    unsigned short* fc2w_bf  = (unsigned short*)alloc((size_t)1048576 * 2);
    unsigned short* ybf      = (unsigned short*)alloc((size_t)1048576 * 2);
    unsigned short* h1bf     = (unsigned short*)alloc((size_t)1048576 * 2);
    unsigned short* h2bf     = (unsigned short*)alloc((size_t)1048576 * 2);

    if (tier == 1) {
        // feature transpose (BW-bound, 512 B granules)
        hipLaunchKernelGGL(feat_tr_kernel, dim3(680), dim3(256), 0, stream,
                           feat2, feat3, feat4, feat5, T);
        // roi gather (latency-bound) + convw transpose + fc cvts (BW-bound), co-resident
        hipLaunchKernelGGL(gather_prep_kernel, dim3(3584), dim3(256), 0, stream,
                           T, rois, pooled, nroi,
                           conv_w, convw_bf, fc1_w, fc1w_bf, fc2_w, fc2w_bf);
    } else {
        hipLaunchKernelGGL(wprep_kernel, dim3(2560), dim3(256), 0, stream,
                           conv_w, convw_bf, fc1_w, fc1w_bf, fc2_w, fc2w_bf);
        hipLaunchKernelGGL(roi_direct_kernel, dim3(1024), dim3(256), 0, stream,
                           feat2, feat3, feat4, feat5, rois, pooled, nroi);
    }

    // conv einsum GEMM, double-buffered split-K (XCD-aligned when nz==8)
    hipLaunchKernelGGL(gemm_bt, dim3(64 * nzc), dim3(256), 0, stream,
                       pooled, convw_bf, part, POOLK, Kper, nzc);
    hipLaunchKernelGGL(reduce_bn_kernel, dim3(1024), dim3(256), 0, stream,
                       part, conv_b, bn_gamma, bn_beta, bn_mean, bn_var, ybf, nzc);

    // fc1 + relu, fc2 + relu
    hipLaunchKernelGGL(gemm64_fused, dim3(16, 16), dim3(256), 0, stream,
                       ybf, fc1w_bf, fc1_b, h1bf, 1);
    hipLaunchKernelGGL(gemm64_fused, dim3(16, 16), dim3(256), 0, stream,
                       h1bf, fc2w_bf, fc2_b, h2bf, 1);

    // heads + softmax
    hipLaunchKernelGGL(head_kernel, dim3(250), dim3(256), 0, stream,
                       h2bf, cls_w, cls_b, bbox_w, bbox_b, out);
}

// Round 6
// 125.148 us; speedup vs baseline: 1.0499x; 1.0499x over previous
//
#include <hip/hip_runtime.h>
#include <cstdint>
#include <cstddef>

typedef __attribute__((ext_vector_type(8))) short bf16x8;
typedef __attribute__((ext_vector_type(4))) float f32x4;

#define POOLK 12544   // K order: ij*256 + c

// T (channel-last bf16 feats) level offsets in shorts
#define TOFF2 0
#define TOFF3 16777216
#define TOFF4 20971520
#define TOFF5 22020096

__device__ __forceinline__ void gld16(const void* g, void* l) {
    __builtin_amdgcn_global_load_lds(
        (const __attribute__((address_space(1))) void*)g,
        (__attribute__((address_space(3))) void*)l, 16, 0, 0);
}
__device__ __forceinline__ unsigned short f32_to_bf16(float f) {
    union { float f; unsigned u; } x; x.f = f;
    return (unsigned short)((x.u + 0x7FFFu + ((x.u >> 16) & 1u)) >> 16);
}
__device__ __forceinline__ float bf16_to_f32(unsigned short s) {
    return __uint_as_float(((unsigned)s) << 16);
}

// ---------- feature transpose, 128-pos tiles: [256][HW] f32 -> [HW][256] bf16 ----------
__global__ __launch_bounds__(256) void feat_tr_kernel(
    const float* __restrict__ f2, const float* __restrict__ f3,
    const float* __restrict__ f4, const float* __restrict__ f5,
    unsigned short* __restrict__ T)
{
    __shared__ __align__(16) unsigned short sh[128 * 256];   // 64 KB
    int b = blockIdx.x;
    const float* src; unsigned short* dst; int P;
    if (b < 512)      { src = f2; dst = T + TOFF2; P = 65536; }
    else if (b < 640) { src = f3; dst = T + TOFF3; P = 16384; b -= 512; }
    else if (b < 672) { src = f4; dst = T + TOFF4; P = 4096;  b -= 640; }
    else              { src = f5; dst = T + TOFF5; P = 1024;  b -= 672; }
    const int p0 = b * 128;
    const int t = threadIdx.x;
    const int lane5 = t & 31;
    const int x4 = lane5 * 4;
    const int fx = (lane5 & 7) << 3;

#pragma unroll
    for (int it = 0; it < 8; ++it) {
        float4 v[4];
        int cs[4];
#pragma unroll
        for (int u = 0; u < 4; ++u) {
            cs[u] = it * 32 + u * 8 + (t >> 5);
            v[u] = *(const float4*)(src + (size_t)cs[u] * P + p0 + x4);
        }
#pragma unroll
        for (int u = 0; u < 4; ++u) {
            const int cp = cs[u] ^ fx;
            float vv[4] = {v[u].x, v[u].y, v[u].z, v[u].w};
#pragma unroll
            for (int i = 0; i < 4; ++i)
                sh[(x4 + i) * 256 + cp] = f32_to_bf16(vv[i]);
        }
    }
    __syncthreads();

    const int c0 = lane5 * 8;
#pragma unroll
    for (int oz = 0; oz < 16; ++oz) {
        const int pp = oz * 8 + (t >> 5);
        const int cr = c0 ^ (((pp >> 2) & 7) << 3);
        const bf16x8 vv = *(const bf16x8*)&sh[pp * 256 + cr];
        *(bf16x8*)(dst + (size_t)(p0 + pp) * 256 + c0) = vv;
    }
}

// ---------- merged: ROI gather (blocks 0-1023) + convw transpose + fc cvts ----------
__global__ __launch_bounds__(256) void gather_prep_kernel(
    const unsigned short* __restrict__ T, const float* __restrict__ rois,
    unsigned short* __restrict__ pooled, int nroi,
    const float* __restrict__ conv_w, unsigned short* __restrict__ convw_bf,
    const float* __restrict__ fc1_w, unsigned short* __restrict__ fc1w_bf,
    const float* __restrict__ fc2_w, unsigned short* __restrict__ fc2w_bf)
{
    const int t = threadIdx.x;
    int b = blockIdx.x;

    if (b >= 1024) {
        b -= 1024;
        if (b < 2048) {          // conv_w [o][c][ij] -> [o][ij*256+c], half per block
            __shared__ unsigned short sh[6272];
            const int o = b >> 1, half = b & 1;
            const float* srow = conv_w + (size_t)o * POOLK + half * 6272;
            for (int k = t; k < 6272; k += 256) sh[k] = f32_to_bf16(srow[k]);
            __syncthreads();
            unsigned short* drow = convw_bf + (size_t)o * POOLK + half * 128;
            for (int k = t; k < 6272; k += 256) {
                const int ij = k >> 7, cl = k & 127;
                drow[ij * 256 + cl] = sh[cl * 49 + ij];
            }
        } else {                 // fc weight conversions
            b -= 2048;
            const float* src = (b < 256) ? fc1_w : fc2_w;
            unsigned short* dst = (b < 256) ? fc1w_bf : fc2w_bf;
            const int base = (b & 255) * 4096 + t * 16;
#pragma unroll
            for (int u = 0; u < 4; ++u) {
                const float4 v = *(const float4*)(src + base + u * 4);
                ushort4 o4;
                o4.x = f32_to_bf16(v.x); o4.y = f32_to_bf16(v.y);
                o4.z = f32_to_bf16(v.z); o4.w = f32_to_bf16(v.w);
                *(ushort4*)(dst + base + u * 4) = o4;
            }
        }
        return;
    }

    // ROI gather from channel-last T; pooled[n][ij*256+c]; zero pad rows
    const int n = b;
    unsigned short* orow = pooled + (size_t)n * POOLK;
    if (n >= nroi) {
        const bf16x8 z = {};
        for (int k = t * 8; k < POOLK; k += 2048) *(bf16x8*)(orow + k) = z;
        return;
    }
    __shared__ int sy0[7], sy1[7], sx0[7], sx1[7];
    __shared__ float swy[7], swx[7], svy[7], svx[7];

    const float rx1 = rois[n*4+0], ry1 = rois[n*4+1];
    const float rx2 = rois[n*4+2], ry2 = rois[n*4+3];
    int lvl = (int)rintf(log2f(sqrtf((ry2-ry1)*(rx2-rx1)) * (1.0f/224.0f))) + 4;
    lvl = lvl < 2 ? 2 : (lvl > 5 ? 5 : lvl);
    const int W = 256 >> (lvl - 2);
    const float Hm1 = (float)(W - 1);
    const unsigned short* Tl = T + (lvl == 2 ? TOFF2 : (lvl == 3 ? TOFF3 : (lvl == 4 ? TOFF4 : TOFF5)));

    if (t < 7) {
        const float tt = (float)t / 6.0f;
        const float by1 = ry1*(1.0f/1024.0f), by2 = ry2*(1.0f/1024.0f);
        const float bx1 = rx1*(1.0f/1024.0f), bx2 = rx2*(1.0f/1024.0f);
        const float ys = (by1 + (by2 - by1) * tt) * Hm1;
        const float xs = (bx1 + (bx2 - bx1) * tt) * Hm1;
        const float yf = floorf(ys), xf = floorf(xs);
        swy[t] = ys - yf;  swx[t] = xs - xf;
        sy0[t] = (int)fminf(fmaxf(yf,        0.0f), Hm1);
        sy1[t] = (int)fminf(fmaxf(yf + 1.0f, 0.0f), Hm1);
        sx0[t] = (int)fminf(fmaxf(xf,        0.0f), Hm1);
        sx1[t] = (int)fminf(fmaxf(xf + 1.0f, 0.0f), Hm1);
        svy[t] = (ys >= 0.0f && ys <= Hm1) ? 1.0f : 0.0f;
        svx[t] = (xs >= 0.0f && xs <= Hm1) ? 1.0f : 0.0f;
    }
    __syncthreads();

    const int g  = t >> 5;
    const int c0 = (t & 31) * 8;
#pragma unroll
    for (int it = 0; it < 7; ++it) {
        const int pos = it * 8 + g;
        if (pos >= 49) break;
        const int i = pos / 7, j = pos % 7;
        const int y0 = sy0[i], y1 = sy1[i], x0 = sx0[j], x1 = sx1[j];
        const float wy = swy[i], wx = swx[j];
        const float scale = svy[i] * svx[j];
        const bf16x8 v00 = *(const bf16x8*)(Tl + ((size_t)(y0*W + x0))*256 + c0);
        const bf16x8 v01 = *(const bf16x8*)(Tl + ((size_t)(y0*W + x1))*256 + c0);
        const bf16x8 v10 = *(const bf16x8*)(Tl + ((size_t)(y1*W + x0))*256 + c0);
        const bf16x8 v11 = *(const bf16x8*)(Tl + ((size_t)(y1*W + x1))*256 + c0);
        bf16x8 o;
#pragma unroll
        for (int jj = 0; jj < 8; ++jj) {
            const float f00 = bf16_to_f32((unsigned short)v00[jj]);
            const float f01 = bf16_to_f32((unsigned short)v01[jj]);
            const float f10 = bf16_to_f32((unsigned short)v10[jj]);
            const float f11 = bf16_to_f32((unsigned short)v11[jj]);
            const float top = f00 + (f01 - f00) * wx;
            const float bot = f10 + (f11 - f10) * wx;
            o[jj] = (short)f32_to_bf16((top + (bot - top) * wy) * scale);
        }
        *(bf16x8*)(orow + pos * 256 + c0) = o;
    }
}

// ---------- fallback ROI (direct f32 gather), also zeroes pad rows ----------
__global__ __launch_bounds__(256) void roi_direct_kernel(
    const float* __restrict__ feat2, const float* __restrict__ feat3,
    const float* __restrict__ feat4, const float* __restrict__ feat5,
    const float* __restrict__ rois, unsigned short* __restrict__ pooled, int nroi)
{
    const int n = blockIdx.x;
    const int tid = threadIdx.x;
    unsigned short* orow = pooled + (size_t)n * POOLK;
    if (n >= nroi) {
        const bf16x8 z = {};
        for (int k = tid * 8; k < POOLK; k += 2048) *(bf16x8*)(orow + k) = z;
        return;
    }
    __shared__ int sy0[7], sy1[7], sx0[7], sx1[7];
    __shared__ float swy[7], swx[7], svy[7], svx[7];
    const float rx1 = rois[n*4+0], ry1 = rois[n*4+1];
    const float rx2 = rois[n*4+2], ry2 = rois[n*4+3];
    int lvl = (int)rintf(log2f(sqrtf((ry2-ry1)*(rx2-rx1)) * (1.0f/224.0f))) + 4;
    lvl = lvl < 2 ? 2 : (lvl > 5 ? 5 : lvl);
    const int H = 256 >> (lvl - 2);
    const float Hm1 = (float)(H - 1);
    const float* feat = lvl==2 ? feat2 : (lvl==3 ? feat3 : (lvl==4 ? feat4 : feat5));
    if (tid < 7) {
        const float t = (float)tid / 6.0f;
        const float by1 = ry1*(1.0f/1024.0f), by2 = ry2*(1.0f/1024.0f);
        const float bx1 = rx1*(1.0f/1024.0f), bx2 = rx2*(1.0f/1024.0f);
        const float ys = (by1 + (by2-by1)*t) * Hm1;
        const float xs = (bx1 + (bx2-bx1)*t) * Hm1;
        const float yf = floorf(ys), xf = floorf(xs);
        swy[tid] = ys - yf;  swx[tid] = xs - xf;
        sy0[tid] = (int)fminf(fmaxf(yf,      0.0f), Hm1);
        sy1[tid] = (int)fminf(fmaxf(yf+1.0f, 0.0f), Hm1);
        sx0[tid] = (int)fminf(fmaxf(xf,      0.0f), Hm1);
        sx1[tid] = (int)fminf(fmaxf(xf+1.0f, 0.0f), Hm1);
        svy[tid] = (ys >= 0.0f && ys <= Hm1) ? 1.0f : 0.0f;
        svx[tid] = (xs >= 0.0f && xs <= Hm1) ? 1.0f : 0.0f;
    }
    __syncthreads();
    const int HW = H * H;
    for (int e = tid; e < POOLK; e += 256) {
        const int c = e / 49, ij = e % 49, i = ij / 7, j = ij % 7;
        const float* p = feat + c * HW;
        const int y0 = sy0[i], y1 = sy1[i], x0 = sx0[j], x1 = sx1[j];
        const float wy = swy[i], wx = swx[j];
        const float v00 = p[y0*H + x0], v01 = p[y0*H + x1];
        const float v10 = p[y1*H + x0], v11 = p[y1*H + x1];
        float v = v00*(1.0f-wy)*(1.0f-wx) + v01*(1.0f-wy)*wx
                + v10*wy*(1.0f-wx)        + v11*wy*wx;
        v *= svy[i] * svx[j];
        orow[ij*256 + c] = f32_to_bf16(v);
    }
}

// ---------- direct-path weight prep (tier 2 only) ----------
__global__ __launch_bounds__(256) void wprep_kernel(
    const float* __restrict__ conv_w, unsigned short* __restrict__ convw_bf,
    const float* __restrict__ fc1_w, unsigned short* __restrict__ fc1w_bf,
    const float* __restrict__ fc2_w, unsigned short* __restrict__ fc2w_bf)
{
    const int t = threadIdx.x;
    int b = blockIdx.x;
    if (b < 2048) {
        __shared__ unsigned short sh[6272];
        const int o = b >> 1, half = b & 1;
        const float* srow = conv_w + (size_t)o * POOLK + half * 6272;
        for (int k = t; k < 6272; k += 256) sh[k] = f32_to_bf16(srow[k]);
        __syncthreads();
        unsigned short* drow = convw_bf + (size_t)o * POOLK + half * 128;
        for (int k = t; k < 6272; k += 256) {
            const int ij = k >> 7, cl = k & 127;
            drow[ij * 256 + cl] = sh[cl * 49 + ij];
        }
        return;
    }
    b -= 2048;
    const float* src = (b < 256) ? fc1_w : fc2_w;
    unsigned short* dst = (b < 256) ? fc1w_bf : fc2w_bf;
    const int base = (b & 255) * 4096 + t * 16;
#pragma unroll
    for (int u = 0; u < 4; ++u) {
        const float4 v = *(const float4*)(src + base + u * 4);
        ushort4 o4;
        o4.x = f32_to_bf16(v.x); o4.y = f32_to_bf16(v.y);
        o4.z = f32_to_bf16(v.z); o4.w = f32_to_bf16(v.w);
        *(ushort4*)(dst + base + u * 4) = o4;
    }
}

// ---------- bf16 BT-GEMM, 128x128 tile, BK=64, dbuf + raw barrier + counted vmcnt ----------
// Conflict-free LDS: row stride 128 B, slot swizzle (slot ^ (row&7)). Raw s_barrier
// (no implicit vmcnt(0) drain) keeps next tile's 8 global_load_lds in flight: vmcnt(8).
__global__ __launch_bounds__(256, 2) void gemm_bt(
    const unsigned short* __restrict__ A, const unsigned short* __restrict__ B,
    float* __restrict__ Cpart, int K, int Kper, int nz)
{
    __shared__ __align__(16) unsigned short At[2][128*64];   // 32 KB
    __shared__ __align__(16) unsigned short Bt[2][128*64];   // 32 KB
    const int tid  = threadIdx.x;
    const int lane = tid & 63;
    const int bid  = blockIdx.x;
    const int z  = bid % nz;
    const int iq = bid / nz;
    const int bx = iq & 7, by = iq >> 3;
    const int wm = (tid >> 6) >> 1, wn = (tid >> 6) & 1;
    const size_t k0 = (size_t)z * Kper;

    const int r1 = tid >> 3;           // 0..31
    const int q  = tid & 7;
    const int csw = (q ^ (r1 & 7)) * 8;     // inverse-swizzled global column
    const unsigned short* Ag = A + ((size_t)(by * 128 + r1)) * K + k0 + csw;
    const unsigned short* Bg = B + ((size_t)(bx * 128 + r1)) * K + k0 + csw;
    const int nit = (Kper + 63) >> 6;

#pragma unroll
    for (int p = 0; p < 4; ++p) {
        gld16(Ag + (size_t)(32 * p) * K, &At[0][p * 2048 + tid * 8]);
        gld16(Bg + (size_t)(32 * p) * K, &Bt[0][p * 2048 + tid * 8]);
    }

    f32x4 acc[4][4] = {};
    const int fr = lane & 15;
    const int fq = lane >> 4;
    const int sA = fr & 7;

    int buf = 0;
    for (int it = 0; it < nit; ++it) {
        const int k = it << 6;
        if (it + 1 < nit) {
            const size_t ko = (size_t)(k + 64);
#pragma unroll
            for (int p = 0; p < 4; ++p) {
                gld16(Ag + (size_t)(32 * p) * K + ko, &At[buf ^ 1][p * 2048 + tid * 8]);
                gld16(Bg + (size_t)(32 * p) * K + ko, &Bt[buf ^ 1][p * 2048 + tid * 8]);
            }
            asm volatile("s_waitcnt vmcnt(8)" ::: "memory");
        } else {
            asm volatile("s_waitcnt vmcnt(0)" ::: "memory");
        }
        __builtin_amdgcn_sched_barrier(0);
        __builtin_amdgcn_s_barrier();
        __builtin_amdgcn_sched_barrier(0);

        bf16x8 a[4][2], b[4][2];
#pragma unroll
        for (int mi = 0; mi < 4; ++mi) {
            const int row = wm * 64 + mi * 16 + fr;
#pragma unroll
            for (int kk = 0; kk < 2; ++kk)
                a[mi][kk] = *(const bf16x8*)&At[buf][row * 64 + ((kk * 4 + fq) ^ sA) * 8];
        }
#pragma unroll
        for (int ni = 0; ni < 4; ++ni) {
            const int row = wn * 64 + ni * 16 + fr;
#pragma unroll
            for (int kk = 0; kk < 2; ++kk)
                b[ni][kk] = *(const bf16x8*)&Bt[buf][row * 64 + ((kk * 4 + fq) ^ sA) * 8];
        }
        __builtin_amdgcn_s_setprio(1);
#pragma unroll
        for (int mi = 0; mi < 4; ++mi)
#pragma unroll
            for (int ni = 0; ni < 4; ++ni)
                acc[mi][ni] = __builtin_amdgcn_mfma_f32_16x16x32_bf16(
                    a[mi][0], b[ni][0], acc[mi][ni], 0, 0, 0);
        if (k + 32 < Kper) {
#pragma unroll
            for (int mi = 0; mi < 4; ++mi)
#pragma unroll
                for (int ni = 0; ni < 4; ++ni)
                    acc[mi][ni] = __builtin_amdgcn_mfma_f32_16x16x32_bf16(
                        a[mi][1], b[ni][1], acc[mi][ni], 0, 0, 0);
        }
        __builtin_amdgcn_s_setprio(0);
        __builtin_amdgcn_sched_barrier(0);
        __builtin_amdgcn_s_barrier();
        __builtin_amdgcn_sched_barrier(0);
        buf ^= 1;
    }

    float* Cp = Cpart + (size_t)z * (1024 * 1024);
    const int row0 = by * 128 + wm * 64;
    const int col0 = bx * 128 + wn * 64;
#pragma unroll
    for (int mi = 0; mi < 4; ++mi)
#pragma unroll
        for (int ni = 0; ni < 4; ++ni)
#pragma unroll
            for (int r = 0; r < 4; ++r)
                Cp[(size_t)(row0 + mi*16 + fq*4 + r) * 1024 + col0 + ni*16 + fr]
                    = acc[mi][ni][r];
}

// ---------- reduce split-K partials + BN -> bf16 ----------
__global__ void reduce_bn_kernel(const float* __restrict__ part,
    const float* __restrict__ bias, const float* __restrict__ gamma,
    const float* __restrict__ beta, const float* __restrict__ mean,
    const float* __restrict__ var, unsigned short* __restrict__ out, int nz)
{
    const int i4 = (blockIdx.x * 256 + threadIdx.x) * 4;
    const int n = i4 & 1023;
    float4 v = make_float4(0.f, 0.f, 0.f, 0.f);
    for (int zz = 0; zz < nz; ++zz) {
        const float4 p = *(const float4*)(part + (size_t)zz * 1048576 + i4);
        v.x += p.x; v.y += p.y; v.z += p.z; v.w += p.w;
    }
    const float4 bi = *(const float4*)(bias + n);
    const float4 ga = *(const float4*)(gamma + n);
    const float4 be = *(const float4*)(beta + n);
    const float4 me = *(const float4*)(mean + n);
    const float4 va = *(const float4*)(var + n);
    ushort4 o;
    o.x = f32_to_bf16((v.x + bi.x - me.x) * __frsqrt_rn(va.x + 0.001f) * ga.x + be.x);
    o.y = f32_to_bf16((v.y + bi.y - me.y) * __frsqrt_rn(va.y + 0.001f) * ga.y + be.y);
    o.z = f32_to_bf16((v.z + bi.z - me.z) * __frsqrt_rn(va.z + 0.001f) * ga.z + be.z);
    o.w = f32_to_bf16((v.w + bi.w - me.w) * __frsqrt_rn(va.w + 0.001f) * ga.w + be.w);
    *(ushort4*)(out + i4) = o;
}

// ---------- fused 64x64 FC GEMM (K=1024, BK=64, dbuf + raw barrier) ----------
__global__ __launch_bounds__(256) void gemm64_fused(
    const unsigned short* __restrict__ A, const unsigned short* __restrict__ B,
    const float* __restrict__ bias, unsigned short* __restrict__ out, int relu)
{
    __shared__ __align__(16) unsigned short At[2][64*64];
    __shared__ __align__(16) unsigned short Bt[2][64*64];
    const int tid = threadIdx.x, lane = tid & 63;
    const int w = tid >> 6, wm = w >> 1, wn = w & 1;
    const int r1 = tid >> 3;           // 0..31
    const int q  = tid & 7;
    const int csw = (q ^ (r1 & 7)) * 8;
    const unsigned short* Ag = A + (size_t)(blockIdx.y*64 + r1) * 1024 + csw;
    const unsigned short* Bg = B + (size_t)(blockIdx.x*64 + r1) * 1024 + csw;
    const int fr = lane & 15, fq = lane >> 4;
    const int sA = fr & 7;

#pragma unroll
    for (int p = 0; p < 2; ++p) {
        gld16(Ag + (size_t)(32 * p) * 1024, &At[0][p * 2048 + tid * 8]);
        gld16(Bg + (size_t)(32 * p) * 1024, &Bt[0][p * 2048 + tid * 8]);
    }

    f32x4 acc[2][2] = {};
    int buf = 0;
    for (int it = 0; it < 16; ++it) {
        if (it + 1 < 16) {
            const int ko = (it + 1) * 64;
#pragma unroll
            for (int p = 0; p < 2; ++p) {
                gld16(Ag + (size_t)(32 * p) * 1024 + ko, &At[buf ^ 1][p * 2048 + tid * 8]);
                gld16(Bg + (size_t)(32 * p) * 1024 + ko, &Bt[buf ^ 1][p * 2048 + tid * 8]);
            }
            asm volatile("s_waitcnt vmcnt(4)" ::: "memory");
        } else {
            asm volatile("s_waitcnt vmcnt(0)" ::: "memory");
        }
        __builtin_amdgcn_sched_barrier(0);
        __builtin_amdgcn_s_barrier();
        __builtin_amdgcn_sched_barrier(0);

        bf16x8 a[2][2], b[2][2];
#pragma unroll
        for (int mi = 0; mi < 2; ++mi) {
            const int row = wm * 32 + mi * 16 + fr;
#pragma unroll
            for (int kk = 0; kk < 2; ++kk)
                a[mi][kk] = *(const bf16x8*)&At[buf][row * 64 + ((kk * 4 + fq) ^ sA) * 8];
        }
#pragma unroll
        for (int ni = 0; ni < 2; ++ni) {
            const int row = wn * 32 + ni * 16 + fr;
#pragma unroll
            for (int kk = 0; kk < 2; ++kk)
                b[ni][kk] = *(const bf16x8*)&Bt[buf][row * 64 + ((kk * 4 + fq) ^ sA) * 8];
        }
        __builtin_amdgcn_s_setprio(1);
#pragma unroll
        for (int kk = 0; kk < 2; ++kk)
#pragma unroll
            for (int mi = 0; mi < 2; ++mi)
#pragma unroll
                for (int ni = 0; ni < 2; ++ni)
                    acc[mi][ni] = __builtin_amdgcn_mfma_f32_16x16x32_bf16(
                        a[mi][kk], b[ni][kk], acc[mi][ni], 0, 0, 0);
        __builtin_amdgcn_s_setprio(0);
        __builtin_amdgcn_sched_barrier(0);
        __builtin_amdgcn_s_barrier();
        __builtin_amdgcn_sched_barrier(0);
        buf ^= 1;
    }
    const int row0 = blockIdx.y*64 + wm*32;
    const int col0 = blockIdx.x*64 + wn*32;
#pragma unroll
    for (int mi = 0; mi < 2; ++mi)
#pragma unroll
        for (int ni = 0; ni < 2; ++ni)
#pragma unroll
            for (int r = 0; r < 4; ++r) {
                const int row = row0 + mi*16 + fq*4 + r;
                const int col = col0 + ni*16 + fr;
                float v = acc[mi][ni][r] + bias[col];
                if (relu) v = fmaxf(v, 0.0f);
                out[(size_t)row * 1024 + col] = f32_to_bf16(v);
            }
}

// ---------- cls/bbox heads + softmax ----------
__global__ __launch_bounds__(256) void head_kernel(
    const unsigned short* __restrict__ h2,
    const float* __restrict__ cls_w, const float* __restrict__ cls_b,
    const float* __restrict__ bbox_w, const float* __restrict__ bbox_b,
    float* __restrict__ out)
{
    const int roi = blockIdx.x * 4 + (threadIdx.x >> 6);
    const int lane = threadIdx.x & 63;
    const unsigned short* hrow = h2 + (size_t)roi * 1024;
    float hv[16];
#pragma unroll
    for (int j = 0; j < 16; ++j)
        hv[j] = bf16_to_f32(hrow[lane*16 + j]);
    float r[10];
#pragma unroll
    for (int o = 0; o < 10; ++o) {
        const float* w = (o < 2) ? (cls_w + o*1024) : (bbox_w + (size_t)(o-2)*1024);
        float s = 0.f;
#pragma unroll
        for (int j = 0; j < 16; ++j) s += hv[j] * w[lane*16 + j];
#pragma unroll
        for (int off = 32; off > 0; off >>= 1) s += __shfl_xor(s, off);
        r[o] = s;
    }
    if (lane == 0) {
        const float l0 = r[0] + cls_b[0], l1 = r[1] + cls_b[1];
        out[roi*2+0] = l0; out[roi*2+1] = l1;
        const float m = fmaxf(l0, l1);
        const float e0 = expf(l0 - m), e1 = expf(l1 - m);
        const float inv = 1.0f / (e0 + e1);
        out[2000 + roi*2 + 0] = e0 * inv;
        out[2000 + roi*2 + 1] = e1 * inv;
#pragma unroll
        for (int qq = 0; qq < 8; ++qq) out[4000 + roi*8 + qq] = r[2+qq] + bbox_b[qq];
    }
}

// ---------- launcher ----------
extern "C" void kernel_launch(void* const* d_in, const int* in_sizes, int n_in,
                              void* d_out, int out_size, void* d_ws, size_t ws_size,
                              hipStream_t stream)
{
    const float* feat2   = (const float*)d_in[0];
    const float* feat3   = (const float*)d_in[1];
    const float* feat4   = (const float*)d_in[2];
    const float* feat5   = (const float*)d_in[3];
    const float* rois    = (const float*)d_in[4];
    const float* conv_w  = (const float*)d_in[5];
    const float* conv_b  = (const float*)d_in[6];
    const float* bn_gamma= (const float*)d_in[7];
    const float* bn_beta = (const float*)d_in[8];
    const float* bn_mean = (const float*)d_in[9];
    const float* bn_var  = (const float*)d_in[10];
    const float* fc1_w   = (const float*)d_in[11];
    const float* fc1_b   = (const float*)d_in[12];
    const float* fc2_w   = (const float*)d_in[13];
    const float* fc2_b   = (const float*)d_in[14];
    const float* cls_w   = (const float*)d_in[15];
    const float* cls_b   = (const float*)d_in[16];
    const float* bbox_w  = (const float*)d_in[17];
    const float* bbox_b  = (const float*)d_in[18];
    float* out = (float*)d_out;
    const int nroi = in_sizes[4] / 4;

    const size_t fixedBytes = (size_t)25690112 + 25690112 + 5 * (size_t)2097152;
    const size_t needA = fixedBytes + (size_t)44564480;   // ~106.5 MB
    const int tier = (ws_size >= needA) ? 1 : 2;
    const size_t regionA = tier == 1 ? (size_t)44564480 : (size_t)16777216;
    const int nzc  = tier == 1 ? 8 : 4;
    const int Kper = tier == 1 ? 1568 : 3136;

    char* ws = (char*)d_ws;
    size_t off = 0;
    auto alloc = [&](size_t bytes) {
        void* p = ws + off; off += (bytes + 255) & ~(size_t)255; return p;
    };
    char* rA = (char*)alloc(regionA);     // T feats (early) aliased by split-K partials (late)
    unsigned short* T    = (unsigned short*)rA;
    float*          part = (float*)rA;
    unsigned short* pooled   = (unsigned short*)alloc((size_t)1024 * POOLK * 2);
    unsigned short* convw_bf = (unsigned short*)alloc((size_t)1024 * POOLK * 2);
    unsigned short* fc1w_bf  = (unsigned short*)alloc((size_t)1048576 * 2);
    unsigned short* fc2w_bf  = (unsigned short*)alloc((size_t)1048576 * 2);
    unsigned short* ybf      = (unsigned short*)alloc((size_t)1048576 * 2);
    unsigned short* h1bf     = (unsigned short*)alloc((size_t)1048576 * 2);
    unsigned short* h2bf     = (unsigned short*)alloc((size_t)1048576 * 2);

    if (tier == 1) {
        hipLaunchKernelGGL(feat_tr_kernel, dim3(680), dim3(256), 0, stream,
                           feat2, feat3, feat4, feat5, T);
        hipLaunchKernelGGL(gather_prep_kernel, dim3(3584), dim3(256), 0, stream,
                           T, rois, pooled, nroi,
                           conv_w, convw_bf, fc1_w, fc1w_bf, fc2_w, fc2w_bf);
    } else {
        hipLaunchKernelGGL(wprep_kernel, dim3(2560), dim3(256), 0, stream,
                           conv_w, convw_bf, fc1_w, fc1w_bf, fc2_w, fc2w_bf);
        hipLaunchKernelGGL(roi_direct_kernel, dim3(1024), dim3(256), 0, stream,
                           feat2, feat3, feat4, feat5, rois, pooled, nroi);
    }

    // conv einsum GEMM, dbuf split-K (XCD-aligned when nz==8)
    hipLaunchKernelGGL(gemm_bt, dim3(64 * nzc), dim3(256), 0, stream,
                       pooled, convw_bf, part, POOLK, Kper, nzc);
    hipLaunchKernelGGL(reduce_bn_kernel, dim3(1024), dim3(256), 0, stream,
                       part, conv_b, bn_gamma, bn_beta, bn_mean, bn_var, ybf, nzc);

    // fc1 + relu, fc2 + relu
    hipLaunchKernelGGL(gemm64_fused, dim3(16, 16), dim3(256), 0, stream,
                       ybf, fc1w_bf, fc1_b, h1bf, 1);
    hipLaunchKernelGGL(gemm64_fused, dim3(16, 16), dim3(256), 0, stream,
                       h1bf, fc2w_bf, fc2_b, h2bf, 1);

    // heads + softmax
    hipLaunchKernelGGL(head_kernel, dim3(250), dim3(256), 0, stream,
                       h2bf, cls_w, cls_b, bbox_w, bbox_b, out);
}